// Round 6
// baseline (181.142 us; speedup 1.0000x reference)
//
#include <hip/hip_runtime.h>
#include <hip/hip_bf16.h>

typedef unsigned short u16;
using f32x4 = __attribute__((ext_vector_type(4))) float;
using short8 = __attribute__((ext_vector_type(8))) short;

constexpr int B_ = 4, N_ = 2048, FIN = 128, H_ = 4, D_ = 32;
constexpr int BH = B_ * H_;
constexpr float LOG2E = 1.4426950408889634f;

// RNE f32 pair -> packed bf16x2 (lo in [15:0], hi in [31:16]); inputs finite.
static __device__ __forceinline__ unsigned int pk_bf16(float lo, float hi) {
  unsigned int ul = __float_as_uint(lo);
  unsigned int uh = __float_as_uint(hi);
  ul = (ul + 0x7fffu + ((ul >> 16) & 1u)) >> 16;
  uh = (uh + 0x7fffu + ((uh >> 16) & 1u)) & 0xffff0000u;
  return ul | uh;
}

// ---------------------------------------------------------------------------
// Kernel 1: WhT (bf16, [bh*D+d][n]) = (h @ W)^T per head, plus e_src/e_dst
// (both pre-scaled by log2e so attn can use exp2 directly).
// ---------------------------------------------------------------------------
constexpr int NPB = 16;  // h-rows per block

__global__ __launch_bounds__(256) void wh_kernel(
    const float* __restrict__ h, const float* __restrict__ W,
    const float* __restrict__ a, u16* __restrict__ WhT,
    float* __restrict__ es, float* __restrict__ ed) {
  __shared__ float hsh[NPB][FIN];
  __shared__ float part[NPB][H_][D_];
  const int t = threadIdx.x;
  const int fh = t >> 7, hh = (t >> 5) & 3, d = t & 31;

  float Wr[64];
#pragma unroll
  for (int ff = 0; ff < 64; ++ff)
    Wr[ff] = W[hh * (FIN * D_) + (fh * 64 + ff) * D_ + d];

  const int n0 = blockIdx.x * NPB;
  for (int idx = t; idx < NPB * FIN; idx += 256)
    hsh[idx >> 7][idx & 127] = h[(size_t)n0 * FIN + idx];
  __syncthreads();

  float accs[NPB];
#pragma unroll
  for (int r = 0; r < NPB; ++r) {
    float acc = 0.f;
    const float* hr = &hsh[r][fh * 64];
#pragma unroll
    for (int f4 = 0; f4 < 16; ++f4) {
      float4 hv = *(const float4*)(hr + f4 * 4);
      acc += hv.x * Wr[f4 * 4 + 0];
      acc += hv.y * Wr[f4 * 4 + 1];
      acc += hv.z * Wr[f4 * 4 + 2];
      acc += hv.w * Wr[f4 * 4 + 3];
    }
    accs[r] = acc;
  }
  if (fh == 0) {
#pragma unroll
    for (int r = 0; r < NPB; ++r) part[r][hh][d] = accs[r];
  }
  __syncthreads();
  if (fh == 1) {
    const int b = n0 / N_;
    const int bh = b * H_ + hh;
    const int n0r = n0 & (N_ - 1);
    const float asrc = a[hh * 2 * D_ + d];
    const float adst = a[hh * 2 * D_ + D_ + d];
    union { u16 s[16]; uint4 q[2]; } wbuf;
#pragma unroll
    for (int r = 0; r < NPB; ++r) {
      const float wh = accs[r] + part[r][hh][d];
      union { __hip_bfloat16 h; u16 u; } cv;
      cv.h = __float2bfloat16(wh);
      wbuf.s[r] = cv.u;
      float vs = wh * asrc, vd = wh * adst;
#pragma unroll
      for (int o = 16; o >= 1; o >>= 1) {
        vs += __shfl_xor(vs, o, 64);
        vd += __shfl_xor(vd, o, 64);
      }
      if (d == 0) {
        es[(size_t)bh * N_ + n0r + r] = vs * LOG2E;
        ed[(size_t)bh * N_ + n0r + r] = vd * LOG2E;
      }
    }
    u16* dst = WhT + ((size_t)(bh * 32 + d)) * N_ + n0r;
    *(uint4*)dst = wbuf.q[0];
    *(uint4*)(dst + 8) = wbuf.q[1];
  }
}

// ---------------------------------------------------------------------------
// Kernel 2: pack adj into a bitmask (u64 word per 64 cols).
// ---------------------------------------------------------------------------
__global__ __launch_bounds__(256) void pack_kernel(
    const int* __restrict__ adj, unsigned long long* __restrict__ mask) {
  const int gid = blockIdx.x * 256 + threadIdx.x;
  const int wdx = gid >> 6;
  const int lane = threadIdx.x & 63;
  const int i = wdx >> 5;
  const int jb = (wdx & 31) << 6;
  const int v = adj[(size_t)i * N_ + jb + lane];
  const unsigned long long m = __ballot(v > 0);
  if (lane == 0) mask[wdx] = m;
}

// ---------------------------------------------------------------------------
// Kernel 3: fused masked-softmax + MFMA PV.
// k-chunk = 128 (4 MFMA substeps) double-buffered: 16 barriers/block vs 64.
// In-block masked rowmax (ed+mask already staged). Epilogue redc overlays
// the dead edsh/mask arena to stay at 3 blocks/CU.
// ---------------------------------------------------------------------------
constexpr int ROWS = 32;
constexpr int CH = 128;            // k per chunk (per j-half)
constexpr int CHP = 136;           // padded shorts per d-row (16B-aligned rows)
constexpr int NCHUNK = 1024 / CH;  // 8 chunks per j-half

__global__ __launch_bounds__(256) void attn_kernel(
    const float* __restrict__ es, const float* __restrict__ ed,
    const u16* __restrict__ WhT, const unsigned int* __restrict__ mask32,
    float* __restrict__ out) {
  // arena: [edsh 8192B | maskw 8320B] then overlaid by [redc 16384B | sumsh]
  __shared__ __align__(16) char arena[16640];
  __shared__ u16 whL[2][2][32 * CHP];  // 34 KB
  __shared__ float essh[ROWS], rmsh[ROWS];

  float* edsh = (float*)arena;
  unsigned int* maskw = (unsigned int*)(arena + 8192);
  unsigned char* maskb = (unsigned char*)(arena + 8192);

  const int bh = blockIdx.x >> 6;
  const int i0 = (blockIdx.x & 63) * ROWS;
  const int tid = threadIdx.x, lane = tid & 63, w = tid >> 6;
  const int tile = w & 1, jh = w >> 1;

  // ---- prologue: stage ed, mask rows, es, chunk-0 Wh ----
  const float* edb = ed + (size_t)bh * N_;
  *(float4*)&edsh[tid * 8] = *(const float4*)(edb + tid * 8);
  *(float4*)&edsh[tid * 8 + 4] = *(const float4*)(edb + tid * 8 + 4);
  const unsigned int* mrow = mask32 + (size_t)i0 * 64;
#pragma unroll
  for (int q = 0; q < 8; ++q) {
    const int idx = tid + q * 256;
    maskw[(idx >> 6) * 65 + (idx & 63)] = mrow[(idx >> 6) * 64 + (idx & 63)];
  }
  if (tid < ROWS) essh[tid] = es[(size_t)bh * N_ + i0 + tid];

  const int jt = tid >> 7;         // j-half this thread stages
  const int sr = (tid >> 2) & 31;  // d-row
  const int sc = tid & 3;          // 16B sub-chunk
  const u16* wsrc = WhT + ((size_t)(bh * 32 + sr)) * N_ + jt * 1024 + sc * 8;
#pragma unroll
  for (int q = 0; q < 4; ++q)
    *(uint4*)&whL[0][jt][sr * CHP + sc * 8 + q * 32] =
        *(const uint4*)(wsrc + q * 32);
  __syncthreads();

  // ---- in-block masked rowmax (scaled domain) ----
#pragma unroll
  for (int q8 = 0; q8 < 8; ++q8) {
    const int r = w * 8 + q8;
    float mx = -3.0e38f;
#pragma unroll
    for (int q = 0; q < 32; ++q) {
      const unsigned int mword = maskw[r * 65 + q * 2 + (lane >> 5)];
      const float v = edsh[q * 64 + lane];
      mx = ((mword >> (lane & 31)) & 1u) ? fmaxf(mx, v) : mx;
    }
#pragma unroll
    for (int o = 32; o >= 1; o >>= 1) mx = fmaxf(mx, __shfl_xor(mx, o, 64));
    if (lane == 0) rmsh[r] = mx;
  }
  __syncthreads();

  const int row16 = lane & 15, kg = lane >> 4;
  const int row32 = tile * 16 + row16;
  const float esr = essh[row32];
  const float xm = esr + rmsh[row32];
  const float mxr = fmaxf(xm, 0.2f * xm);  // exact masked row max (scaled)

  f32x4 c0 = {}, c1 = {};
  float sum = 0.f;
  int cur = 0;

  for (int c = 0; c < NCHUNK; ++c) {
    uint4 nx[4];
    const bool hasnext = (c + 1 < NCHUNK);
    if (hasnext) {
#pragma unroll
      for (int q = 0; q < 4; ++q)
        nx[q] = *(const uint4*)(wsrc + (c + 1) * CH + q * 32);
    }
#pragma unroll
    for (int sub = 0; sub < 4; ++sub) {
      const int k0 = jh * 1024 + c * CH + sub * 32;
      const unsigned int mb = maskb[row32 * 260 + (k0 >> 3) + kg];
      const float4 ea = *(const float4*)&edsh[k0 + kg * 8];
      const float4 eb = *(const float4*)&edsh[k0 + kg * 8 + 4];
      const float ev[8] = {ea.x, ea.y, ea.z, ea.w, eb.x, eb.y, eb.z, eb.w};
      float p[8];
#pragma unroll
      for (int j = 0; j < 8; ++j) {
        const float x = esr + ev[j];
        const float y = fmaxf(x, 0.2f * x);
        float z = fminf(y - mxr, 0.f);
        z = (mb & (1u << j)) ? z : -1e30f;
        const float pj = exp2f(z);
        p[j] = pj;
        sum += pj;
      }
      union { unsigned int u[4]; short8 v8; } af;
      af.u[0] = pk_bf16(p[0], p[1]);
      af.u[1] = pk_bf16(p[2], p[3]);
      af.u[2] = pk_bf16(p[4], p[5]);
      af.u[3] = pk_bf16(p[6], p[7]);

      const u16* bbase = &whL[cur][jh][row16 * CHP + sub * 32 + kg * 8];
      const short8 b0 = *(const short8*)bbase;
      const short8 b1 = *(const short8*)(bbase + 16 * CHP);
      c0 = __builtin_amdgcn_mfma_f32_16x16x32_bf16(af.v8, b0, c0, 0, 0, 0);
      c1 = __builtin_amdgcn_mfma_f32_16x16x32_bf16(af.v8, b1, c1, 0, 0, 0);
    }
    __syncthreads();
    if (hasnext) {
#pragma unroll
      for (int q = 0; q < 4; ++q)
        *(uint4*)&whL[cur ^ 1][jt][sr * CHP + sc * 8 + q * 32] = nx[q];
    }
    __syncthreads();
    cur ^= 1;
  }

  // ---- epilogue: overlay redc onto dead edsh/mask arena ----
  float* redc = (float*)arena;              // [2][2][16][32]
  float* sumsh = (float*)(arena + 16384);   // [2][2][16]
  sum += __shfl_xor(sum, 16, 64);
  sum += __shfl_xor(sum, 32, 64);
  if (lane < 16) sumsh[(tile * 2 + jh) * 16 + lane] = sum;
#pragma unroll
  for (int r = 0; r < 4; ++r) {
    redc[(((tile * 2 + jh) * 16) + kg * 4 + r) * 32 + row16] = c0[r];
    redc[(((tile * 2 + jh) * 16) + kg * 4 + r) * 32 + 16 + row16] = c1[r];
  }
  __syncthreads();

  const int r32 = tid >> 3;
  const int c4 = (tid & 7) * 4;
  const int tl = r32 >> 4, rr = r32 & 15;
  const float inv =
      1.f / fmaxf(sumsh[(tl * 2 + 0) * 16 + rr] + sumsh[(tl * 2 + 1) * 16 + rr],
                  1e-30f);
  const float* r0 = &redc[((tl * 2 + 0) * 16 + rr) * 32 + c4];
  const float* r1 = &redc[((tl * 2 + 1) * 16 + rr) * 32 + c4];
  float4 o;
  o.x = (r0[0] + r1[0]) * inv;
  o.y = (r0[1] + r1[1]) * inv;
  o.z = (r0[2] + r1[2]) * inv;
  o.w = (r0[3] + r1[3]) * inv;
  const int b = bh >> 2, hh = bh & 3;
  *(float4*)&out[((size_t)(b * N_ + i0 + r32)) * (H_ * D_) + hh * 32 + c4] = o;
}

// ---------------------------------------------------------------------------
extern "C" void kernel_launch(void* const* d_in, const int* in_sizes, int n_in,
                              void* d_out, int out_size, void* d_ws,
                              size_t ws_size, hipStream_t stream) {
  const float* h = (const float*)d_in[0];
  const int* adj = (const int*)d_in[1];
  const float* W = (const float*)d_in[2];
  const float* a = (const float*)d_in[3];
  char* ws = (char*)d_ws;
  u16* WhT = (u16*)ws;                                   // 2 MB
  float* es = (float*)(ws + (2u << 20));                 // 128 KB
  float* ed = (float*)(ws + (2u << 20) + (128u << 10));  // 128 KB
  unsigned long long* mask =
      (unsigned long long*)(ws + (2u << 20) + (256u << 10));  // 512 KB
  float* out = (float*)d_out;

  wh_kernel<<<B_ * N_ / NPB, 256, 0, stream>>>(h, W, a, WhT, es, ed);
  pack_kernel<<<N_ * N_ / 256, 256, 0, stream>>>(adj, mask);
  attn_kernel<<<BH * (N_ / ROWS), 256, 0, stream>>>(
      es, ed, WhT, (const unsigned int*)mask, out);
}

// Round 7
// 144.976 us; speedup vs baseline: 1.2495x; 1.2495x over previous
//
#include <hip/hip_runtime.h>
#include <hip/hip_bf16.h>

typedef unsigned short u16;
using f32x4 = __attribute__((ext_vector_type(4))) float;
using short8 = __attribute__((ext_vector_type(8))) short;

constexpr int B_ = 4, N_ = 2048, FIN = 128, H_ = 4, D_ = 32;
constexpr int BH = B_ * H_;
constexpr float LOG2E = 1.4426950408889634f;

// ---------------------------------------------------------------------------
// Kernel 1: WhT (bf16, [bh*D+d][n]) = (h @ W)^T per head, plus e_src/e_dst
// (pre-scaled by log2e so attn uses exp2 directly).
// ---------------------------------------------------------------------------
constexpr int NPB = 16;  // h-rows per block

__global__ __launch_bounds__(256) void wh_kernel(
    const float* __restrict__ h, const float* __restrict__ W,
    const float* __restrict__ a, u16* __restrict__ WhT,
    float* __restrict__ es, float* __restrict__ ed) {
  __shared__ float hsh[NPB][FIN];
  __shared__ float part[NPB][H_][D_];
  const int t = threadIdx.x;
  const int fh = t >> 7, hh = (t >> 5) & 3, d = t & 31;

  float Wr[64];
#pragma unroll
  for (int ff = 0; ff < 64; ++ff)
    Wr[ff] = W[hh * (FIN * D_) + (fh * 64 + ff) * D_ + d];

  const int n0 = blockIdx.x * NPB;
  for (int idx = t; idx < NPB * FIN; idx += 256)
    hsh[idx >> 7][idx & 127] = h[(size_t)n0 * FIN + idx];
  __syncthreads();

  float accs[NPB];
#pragma unroll
  for (int r = 0; r < NPB; ++r) {
    float acc = 0.f;
    const float* hr = &hsh[r][fh * 64];
#pragma unroll
    for (int f4 = 0; f4 < 16; ++f4) {
      float4 hv = *(const float4*)(hr + f4 * 4);
      acc += hv.x * Wr[f4 * 4 + 0];
      acc += hv.y * Wr[f4 * 4 + 1];
      acc += hv.z * Wr[f4 * 4 + 2];
      acc += hv.w * Wr[f4 * 4 + 3];
    }
    accs[r] = acc;
  }
  if (fh == 0) {
#pragma unroll
    for (int r = 0; r < NPB; ++r) part[r][hh][d] = accs[r];
  }
  __syncthreads();
  if (fh == 1) {
    const int b = n0 / N_;
    const int bh = b * H_ + hh;
    const int n0r = n0 & (N_ - 1);
    const float asrc = a[hh * 2 * D_ + d];
    const float adst = a[hh * 2 * D_ + D_ + d];
    union { u16 s[16]; uint4 q[2]; } wbuf;
#pragma unroll
    for (int r = 0; r < NPB; ++r) {
      const float wh = accs[r] + part[r][hh][d];
      union { __hip_bfloat16 h; u16 u; } cv;
      cv.h = __float2bfloat16(wh);
      wbuf.s[r] = cv.u;
      float vs = wh * asrc, vd = wh * adst;
#pragma unroll
      for (int o = 16; o >= 1; o >>= 1) {
        vs += __shfl_xor(vs, o, 64);
        vd += __shfl_xor(vd, o, 64);
      }
      if (d == 0) {
        es[(size_t)bh * N_ + n0r + r] = vs * LOG2E;
        ed[(size_t)bh * N_ + n0r + r] = vd * LOG2E;
      }
    }
    u16* dst = WhT + ((size_t)(bh * 32 + d)) * N_ + n0r;
    *(uint4*)dst = wbuf.q[0];
    *(uint4*)(dst + 8) = wbuf.q[1];
  }
}

// ---------------------------------------------------------------------------
// Kernel 2: pack adj into a bitmask (u64 word per 64 cols).
// ---------------------------------------------------------------------------
__global__ __launch_bounds__(256) void pack_kernel(
    const int* __restrict__ adj, unsigned long long* __restrict__ mask) {
  const int gid = blockIdx.x * 256 + threadIdx.x;
  const int wdx = gid >> 6;
  const int lane = threadIdx.x & 63;
  const int i = wdx >> 5;
  const int jb = (wdx & 31) << 6;
  const int v = adj[(size_t)i * N_ + jb + lane];
  const unsigned long long m = __ballot(v > 0);
  if (lane == 0) mask[wdx] = m;
}

// ---------------------------------------------------------------------------
// Kernel 3: fused masked-softmax + MFMA PV.
// No Wh LDS staging: B-fragments read directly from L2-resident WhT
// (2 MB total; 128 KB per bh), software-pipelined 1 step deep in 2 scalar
// short8 regs (no arrays -> no scratch). Zero barriers in the k-loop.
// ---------------------------------------------------------------------------
constexpr int ROWS = 32;
constexpr int NSTEP = 32;  // 1024 k per j-half / 32

__global__ __launch_bounds__(256) void attn_kernel(
    const float* __restrict__ es, const float* __restrict__ ed,
    const u16* __restrict__ WhT, const unsigned int* __restrict__ mask32,
    float* __restrict__ out) {
  // arena: [edsh 8192B | maskw 8320B], overlaid in epilogue by [redc|sumsh]
  __shared__ __align__(16) char arena[16640];
  __shared__ float essh[ROWS], rmsh[ROWS];

  float* edsh = (float*)arena;
  unsigned int* maskw = (unsigned int*)(arena + 8192);
  unsigned char* maskb = (unsigned char*)(arena + 8192);

  const int bh = blockIdx.x >> 6;
  const int i0 = (blockIdx.x & 63) * ROWS;
  const int tid = threadIdx.x, lane = tid & 63, w = tid >> 6;
  const int tile = w & 1, jh = w >> 1;

  // ---- prologue: stage ed, mask rows, es ----
  const float* edb = ed + (size_t)bh * N_;
  *(float4*)&edsh[tid * 8] = *(const float4*)(edb + tid * 8);
  *(float4*)&edsh[tid * 8 + 4] = *(const float4*)(edb + tid * 8 + 4);
  const unsigned int* mrow = mask32 + (size_t)i0 * 64;
#pragma unroll
  for (int q = 0; q < 8; ++q) {
    const int idx = tid + q * 256;
    maskw[(idx >> 6) * 65 + (idx & 63)] = mrow[(idx >> 6) * 64 + (idx & 63)];
  }
  if (tid < ROWS) essh[tid] = es[(size_t)bh * N_ + i0 + tid];
  __syncthreads();

  // ---- in-block masked rowmax (scaled domain) ----
#pragma unroll
  for (int q8 = 0; q8 < 8; ++q8) {
    const int r = w * 8 + q8;
    float mx = -3.0e38f;
#pragma unroll
    for (int q = 0; q < 32; ++q) {
      const unsigned int mword = maskw[r * 65 + q * 2 + (lane >> 5)];
      const float v = edsh[q * 64 + lane];
      mx = ((mword >> (lane & 31)) & 1u) ? fmaxf(mx, v) : mx;
    }
#pragma unroll
    for (int o = 32; o >= 1; o >>= 1) mx = fmaxf(mx, __shfl_xor(mx, o, 64));
    if (lane == 0) rmsh[r] = mx;
  }
  __syncthreads();

  const int row16 = lane & 15, kg = lane >> 4;
  const int row32 = tile * 16 + row16;
  const float esr = essh[row32];
  const float xm = esr + rmsh[row32];
  const float mxr = fmaxf(xm, 0.2f * xm);  // exact masked row max (scaled)

  // B-fragment base: d-row = row16 (c0) / row16+16 (c1), k offset kg*8.
  const u16* wb0 = WhT + ((size_t)(bh * 32 + row16)) * N_ + jh * 1024 + kg * 8;
  const u16* wb1 = wb0 + (size_t)16 * N_;

  f32x4 c0 = {}, c1 = {};
  float sum = 0.f;
  short8 b0 = *(const short8*)wb0;
  short8 b1 = *(const short8*)wb1;

  for (int s = 0; s < NSTEP; ++s) {
    const int sn = (s + 1 < NSTEP) ? (s + 1) : (NSTEP - 1);
    const short8 nb0 = *(const short8*)(wb0 + sn * 32);
    const short8 nb1 = *(const short8*)(wb1 + sn * 32);

    const int k0 = jh * 1024 + s * 32;
    const unsigned int mb = maskb[row32 * 260 + (k0 >> 3) + kg];
    const float4 ea = *(const float4*)&edsh[k0 + kg * 8];
    const float4 eb = *(const float4*)&edsh[k0 + kg * 8 + 4];
    const float ev[8] = {ea.x, ea.y, ea.z, ea.w, eb.x, eb.y, eb.z, eb.w};
    float p[8];
#pragma unroll
    for (int j = 0; j < 8; ++j) {
      const float x = esr + ev[j];
      const float y = fmaxf(x, 0.2f * x);
      float z = fminf(y - mxr, 0.f);
      z = (mb & (1u << j)) ? z : -1e30f;
      p[j] = exp2f(z);
      sum += p[j];
    }
    union { unsigned int u[4]; short8 v8; } af;
    asm("v_cvt_pk_bf16_f32 %0, %1, %2" : "=v"(af.u[0]) : "v"(p[0]), "v"(p[1]));
    asm("v_cvt_pk_bf16_f32 %0, %1, %2" : "=v"(af.u[1]) : "v"(p[2]), "v"(p[3]));
    asm("v_cvt_pk_bf16_f32 %0, %1, %2" : "=v"(af.u[2]) : "v"(p[4]), "v"(p[5]));
    asm("v_cvt_pk_bf16_f32 %0, %1, %2" : "=v"(af.u[3]) : "v"(p[6]), "v"(p[7]));

    c0 = __builtin_amdgcn_mfma_f32_16x16x32_bf16(af.v8, b0, c0, 0, 0, 0);
    c1 = __builtin_amdgcn_mfma_f32_16x16x32_bf16(af.v8, b1, c1, 0, 0, 0);
    b0 = nb0;
    b1 = nb1;
  }

  __syncthreads();  // everyone done with edsh/mask before overlay

  // ---- epilogue: overlay redc onto dead edsh/mask arena ----
  float* redc = (float*)arena;             // [2][2][16][32]
  float* sumsh = (float*)(arena + 16384);  // [2][2][16]
  sum += __shfl_xor(sum, 16, 64);
  sum += __shfl_xor(sum, 32, 64);
  if (lane < 16) sumsh[(tile * 2 + jh) * 16 + lane] = sum;
#pragma unroll
  for (int r = 0; r < 4; ++r) {
    redc[(((tile * 2 + jh) * 16) + kg * 4 + r) * 32 + row16] = c0[r];
    redc[(((tile * 2 + jh) * 16) + kg * 4 + r) * 32 + 16 + row16] = c1[r];
  }
  __syncthreads();

  const int r32 = tid >> 3;
  const int c4 = (tid & 7) * 4;
  const int tl = r32 >> 4, rr = r32 & 15;
  const float inv =
      1.f / fmaxf(sumsh[(tl * 2 + 0) * 16 + rr] + sumsh[(tl * 2 + 1) * 16 + rr],
                  1e-30f);
  const float* r0 = &redc[((tl * 2 + 0) * 16 + rr) * 32 + c4];
  const float* r1 = &redc[((tl * 2 + 1) * 16 + rr) * 32 + c4];
  float4 o;
  o.x = (r0[0] + r1[0]) * inv;
  o.y = (r0[1] + r1[1]) * inv;
  o.z = (r0[2] + r1[2]) * inv;
  o.w = (r0[3] + r1[3]) * inv;
  const int b = bh >> 2, hh = bh & 3;
  *(float4*)&out[((size_t)(b * N_ + i0 + r32)) * (H_ * D_) + hh * 32 + c4] = o;
}

// ---------------------------------------------------------------------------
extern "C" void kernel_launch(void* const* d_in, const int* in_sizes, int n_in,
                              void* d_out, int out_size, void* d_ws,
                              size_t ws_size, hipStream_t stream) {
  const float* h = (const float*)d_in[0];
  const int* adj = (const int*)d_in[1];
  const float* W = (const float*)d_in[2];
  const float* a = (const float*)d_in[3];
  char* ws = (char*)d_ws;
  u16* WhT = (u16*)ws;                                   // 2 MB
  float* es = (float*)(ws + (2u << 20));                 // 128 KB
  float* ed = (float*)(ws + (2u << 20) + (128u << 10));  // 128 KB
  unsigned long long* mask =
      (unsigned long long*)(ws + (2u << 20) + (256u << 10));  // 512 KB
  float* out = (float*)d_out;

  wh_kernel<<<B_ * N_ / NPB, 256, 0, stream>>>(h, W, a, WhT, es, ed);
  pack_kernel<<<N_ * N_ / 256, 256, 0, stream>>>(adj, mask);
  attn_kernel<<<BH * (N_ / ROWS), 256, 0, stream>>>(
      es, ed, WhT, (const unsigned int*)mask, out);
}

// Round 8
// 133.769 us; speedup vs baseline: 1.3541x; 1.0838x over previous
//
#include <hip/hip_runtime.h>
#include <hip/hip_bf16.h>

typedef unsigned short u16;
using f32x4 = __attribute__((ext_vector_type(4))) float;
using short8 = __attribute__((ext_vector_type(8))) short;

constexpr int B_ = 4, N_ = 2048, FIN = 128, H_ = 4, D_ = 32;
constexpr int BH = B_ * H_;
constexpr float LOG2E = 1.4426950408889634f;

// ---------------------------------------------------------------------------
// Kernel 1: WhT (bf16, [bh*D+d][n]) = (h @ W)^T per head, plus e_src/e_dst
// (pre-scaled by log2e so attn uses exp2 directly).
// ---------------------------------------------------------------------------
constexpr int NPB = 16;  // h-rows per block

__global__ __launch_bounds__(256) void wh_kernel(
    const float* __restrict__ h, const float* __restrict__ W,
    const float* __restrict__ a, u16* __restrict__ WhT,
    float* __restrict__ es, float* __restrict__ ed) {
  __shared__ float hsh[NPB][FIN];
  __shared__ float part[NPB][H_][D_];
  const int t = threadIdx.x;
  const int fh = t >> 7, hh = (t >> 5) & 3, d = t & 31;

  float Wr[64];
#pragma unroll
  for (int ff = 0; ff < 64; ++ff)
    Wr[ff] = W[hh * (FIN * D_) + (fh * 64 + ff) * D_ + d];

  const int n0 = blockIdx.x * NPB;
  for (int idx = t; idx < NPB * FIN; idx += 256)
    hsh[idx >> 7][idx & 127] = h[(size_t)n0 * FIN + idx];
  __syncthreads();

  float accs[NPB];
#pragma unroll
  for (int r = 0; r < NPB; ++r) {
    float acc = 0.f;
    const float* hr = &hsh[r][fh * 64];
#pragma unroll
    for (int f4 = 0; f4 < 16; ++f4) {
      float4 hv = *(const float4*)(hr + f4 * 4);
      acc += hv.x * Wr[f4 * 4 + 0];
      acc += hv.y * Wr[f4 * 4 + 1];
      acc += hv.z * Wr[f4 * 4 + 2];
      acc += hv.w * Wr[f4 * 4 + 3];
    }
    accs[r] = acc;
  }
  if (fh == 0) {
#pragma unroll
    for (int r = 0; r < NPB; ++r) part[r][hh][d] = accs[r];
  }
  __syncthreads();
  if (fh == 1) {
    const int b = n0 / N_;
    const int bh = b * H_ + hh;
    const int n0r = n0 & (N_ - 1);
    const float asrc = a[hh * 2 * D_ + d];
    const float adst = a[hh * 2 * D_ + D_ + d];
    union { u16 s[16]; uint4 q[2]; } wbuf;
#pragma unroll
    for (int r = 0; r < NPB; ++r) {
      const float wh = accs[r] + part[r][hh][d];
      union { __hip_bfloat16 h; u16 u; } cv;
      cv.h = __float2bfloat16(wh);
      wbuf.s[r] = cv.u;
      float vs = wh * asrc, vd = wh * adst;
#pragma unroll
      for (int o = 16; o >= 1; o >>= 1) {
        vs += __shfl_xor(vs, o, 64);
        vd += __shfl_xor(vd, o, 64);
      }
      if (d == 0) {
        es[(size_t)bh * N_ + n0r + r] = vs * LOG2E;
        ed[(size_t)bh * N_ + n0r + r] = vd * LOG2E;
      }
    }
    u16* dst = WhT + ((size_t)(bh * 32 + d)) * N_ + n0r;
    *(uint4*)dst = wbuf.q[0];
    *(uint4*)(dst + 8) = wbuf.q[1];
  }
}

// ---------------------------------------------------------------------------
// Kernel 2: pack adj into a bitmask (u64 word per 64 cols).
// ---------------------------------------------------------------------------
__global__ __launch_bounds__(256) void pack_kernel(
    const int* __restrict__ adj, unsigned long long* __restrict__ mask) {
  const int gid = blockIdx.x * 256 + threadIdx.x;
  const int wdx = gid >> 6;
  const int lane = threadIdx.x & 63;
  const int i = wdx >> 5;
  const int jb = (wdx & 31) << 6;
  const int v = adj[(size_t)i * N_ + jb + lane];
  const unsigned long long m = __ballot(v > 0);
  if (lane == 0) mask[wdx] = m;
}

// ---------------------------------------------------------------------------
// Kernel 3: fused masked-softmax + MFMA PV.
// 16 rows/block, 4 j-quarter waves -> 2048 blocks (8/CU). Direct-L2 B reads.
// Denominator via MFMA against an all-ones B. Tight 2-branch score math.
// ---------------------------------------------------------------------------
constexpr int ROWS = 16;
constexpr int NSTEP = 16;  // 512 k per j-quarter / 32

__global__ __launch_bounds__(256, 6) void attn_kernel(
    const float* __restrict__ es, const float* __restrict__ ed,
    const u16* __restrict__ WhT, const unsigned int* __restrict__ mask32,
    float* __restrict__ out) {
  // arena: [edsh 8192B | maskw 4160B], epilogue overlay: redc [4][16][33] f32
  __shared__ __align__(16) char arena[12352];
  __shared__ float essh[ROWS], rmsh[ROWS];
  __shared__ float sumsh[4][16];

  float* edsh = (float*)arena;
  unsigned int* maskw = (unsigned int*)(arena + 8192);
  unsigned char* maskb = (unsigned char*)(arena + 8192);

  const int bh = blockIdx.x >> 7;  // 128 row-tiles per bh
  const int i0 = (blockIdx.x & 127) * ROWS;
  const int tid = threadIdx.x, lane = tid & 63, w = tid >> 6;
  const int jq = w;  // j-quarter per wave

  // ---- prologue: stage ed, mask rows, es ----
  const float* edb = ed + (size_t)bh * N_;
  *(float4*)&edsh[tid * 8] = *(const float4*)(edb + tid * 8);
  *(float4*)&edsh[tid * 8 + 4] = *(const float4*)(edb + tid * 8 + 4);
  const unsigned int* mrow = mask32 + (size_t)i0 * 64;
#pragma unroll
  for (int q = 0; q < 4; ++q) {
    const int idx = tid + q * 256;
    maskw[(idx >> 6) * 65 + (idx & 63)] = mrow[(idx >> 6) * 64 + (idx & 63)];
  }
  if (tid < ROWS) essh[tid] = es[(size_t)bh * N_ + i0 + tid];
  __syncthreads();

  // ---- in-block masked rowmax (scaled domain) ----
#pragma unroll
  for (int q4 = 0; q4 < 4; ++q4) {
    const int r = w * 4 + q4;
    float mx = -3.0e38f;
#pragma unroll
    for (int q = 0; q < 32; ++q) {
      const unsigned int mword = maskw[r * 65 + q * 2 + (lane >> 5)];
      const float v = edsh[q * 64 + lane];
      mx = ((mword >> (lane & 31)) & 1u) ? fmaxf(mx, v) : mx;
    }
#pragma unroll
    for (int o = 32; o >= 1; o >>= 1) mx = fmaxf(mx, __shfl_xor(mx, o, 64));
    if (lane == 0) rmsh[r] = mx;
  }
  __syncthreads();

  const int row16 = lane & 15, kg = lane >> 4;
  const float esr = essh[row16];
  const float xm = esr + rmsh[row16];
  const float mxr = fmaxf(xm, 0.2f * xm);  // exact masked row max (scaled)
  const float cpos = esr - mxr;            // z_pos = ed + cpos
  const float cneg = 0.2f * esr - mxr;     // z_neg = fma(ed, 0.2, cneg)
  const float thr = -esr;                  // pos branch iff ed >= thr

  // B-fragment base: d-row = row16 (c0) / row16+16 (c1), k offset kg*8.
  const u16* wb0 = WhT + ((size_t)(bh * 32 + row16)) * N_ + jq * 512 + kg * 8;
  const u16* wb1 = wb0 + (size_t)16 * N_;

  // all-ones bf16 B fragment for the denominator MFMA
  short8 ones;
#pragma unroll
  for (int q = 0; q < 8; ++q) ones[q] = (short)0x3F80;

  f32x4 c0 = {}, c1 = {}, csum = {};
  short8 b0 = *(const short8*)wb0;
  short8 b1 = *(const short8*)wb1;

  for (int s = 0; s < NSTEP; ++s) {
    const int sn = (s + 1 < NSTEP) ? (s + 1) : (NSTEP - 1);
    const short8 nb0 = *(const short8*)(wb0 + sn * 32);
    const short8 nb1 = *(const short8*)(wb1 + sn * 32);

    const int k0 = jq * 512 + s * 32;
    const unsigned int mb = maskb[row16 * 260 + (k0 >> 3) + kg];
    const float4 ea = *(const float4*)&edsh[k0 + kg * 8];
    const float4 eb = *(const float4*)&edsh[k0 + kg * 8 + 4];
    const float ev[8] = {ea.x, ea.y, ea.z, ea.w, eb.x, eb.y, eb.z, eb.w};
    float p[8];
#pragma unroll
    for (int j = 0; j < 8; ++j) {
      const float edv = ev[j];
      const float zp = edv + cpos;
      const float zn = __builtin_fmaf(edv, 0.2f, cneg);
      float z = (edv >= thr) ? zp : zn;
      z = (mb & (1u << j)) ? z : -1e30f;
      p[j] = exp2f(z);
    }
    union { unsigned int u[4]; short8 v8; } af;
    asm("v_cvt_pk_bf16_f32 %0, %1, %2" : "=v"(af.u[0]) : "v"(p[0]), "v"(p[1]));
    asm("v_cvt_pk_bf16_f32 %0, %1, %2" : "=v"(af.u[1]) : "v"(p[2]), "v"(p[3]));
    asm("v_cvt_pk_bf16_f32 %0, %1, %2" : "=v"(af.u[2]) : "v"(p[4]), "v"(p[5]));
    asm("v_cvt_pk_bf16_f32 %0, %1, %2" : "=v"(af.u[3]) : "v"(p[6]), "v"(p[7]));

    c0 = __builtin_amdgcn_mfma_f32_16x16x32_bf16(af.v8, b0, c0, 0, 0, 0);
    c1 = __builtin_amdgcn_mfma_f32_16x16x32_bf16(af.v8, b1, c1, 0, 0, 0);
    csum = __builtin_amdgcn_mfma_f32_16x16x32_bf16(af.v8, ones, csum, 0, 0, 0);
    b0 = nb0;
    b1 = nb1;
  }

  __syncthreads();  // edsh/mask dead from here

  // ---- epilogue: overlay redc onto arena; combine 4 j-quarters ----
  float* redc = (float*)arena;  // [4][16][33]
#pragma unroll
  for (int r = 0; r < 4; ++r) {
    redc[(jq * 16 + kg * 4 + r) * 33 + row16] = c0[r];
    redc[(jq * 16 + kg * 4 + r) * 33 + 16 + row16] = c1[r];
  }
  if (row16 == 0) {
#pragma unroll
    for (int r = 0; r < 4; ++r) sumsh[jq][kg * 4 + r] = csum[r];
  }
  __syncthreads();

  if (tid < 128) {
    const int r = tid >> 3;
    const int c4 = (tid & 7) * 4;
    const float inv =
        1.f / fmaxf(sumsh[0][r] + sumsh[1][r] + sumsh[2][r] + sumsh[3][r],
                    1e-30f);
    float4 o;
    const float* p0 = &redc[(0 * 16 + r) * 33 + c4];
    const float* p1 = &redc[(1 * 16 + r) * 33 + c4];
    const float* p2 = &redc[(2 * 16 + r) * 33 + c4];
    const float* p3 = &redc[(3 * 16 + r) * 33 + c4];
    o.x = (p0[0] + p1[0] + p2[0] + p3[0]) * inv;
    o.y = (p0[1] + p1[1] + p2[1] + p3[1]) * inv;
    o.z = (p0[2] + p1[2] + p2[2] + p3[2]) * inv;
    o.w = (p0[3] + p1[3] + p2[3] + p3[3]) * inv;
    const int b = bh >> 2, hh = bh & 3;
    *(float4*)&out[((size_t)(b * N_ + i0 + r)) * (H_ * D_) + hh * 32 + c4] = o;
  }
}

// ---------------------------------------------------------------------------
extern "C" void kernel_launch(void* const* d_in, const int* in_sizes, int n_in,
                              void* d_out, int out_size, void* d_ws,
                              size_t ws_size, hipStream_t stream) {
  const float* h = (const float*)d_in[0];
  const int* adj = (const int*)d_in[1];
  const float* W = (const float*)d_in[2];
  const float* a = (const float*)d_in[3];
  char* ws = (char*)d_ws;
  u16* WhT = (u16*)ws;                                   // 2 MB
  float* es = (float*)(ws + (2u << 20));                 // 128 KB
  float* ed = (float*)(ws + (2u << 20) + (128u << 10));  // 128 KB
  unsigned long long* mask =
      (unsigned long long*)(ws + (2u << 20) + (256u << 10));  // 512 KB
  float* out = (float*)d_out;

  wh_kernel<<<B_ * N_ / NPB, 256, 0, stream>>>(h, W, a, WhT, es, ed);
  pack_kernel<<<N_ * N_ / 256, 256, 0, stream>>>(adj, mask);
  attn_kernel<<<BH * (N_ / ROWS), 256, 0, stream>>>(
      es, ed, WhT, (const unsigned int*)mask, out);
}

// Round 9
// 125.453 us; speedup vs baseline: 1.4439x; 1.0663x over previous
//
#include <hip/hip_runtime.h>
#include <hip/hip_bf16.h>

typedef unsigned short u16;
using f32x4 = __attribute__((ext_vector_type(4))) float;
using short8 = __attribute__((ext_vector_type(8))) short;

constexpr int B_ = 4, N_ = 2048, FIN = 128, H_ = 4, D_ = 32;
constexpr int BH = B_ * H_;
constexpr float LOG2E = 1.4426950408889634f;

// bit-select: m is 0 or -1 per lane; returns m ? a : b.  Folds to v_bfi_b32.
static __device__ __forceinline__ float bitsel(int m, float a, unsigned int bu) {
  return __uint_as_float((__float_as_uint(a) & (unsigned)m) | (bu & ~(unsigned)m));
}

// ---------------------------------------------------------------------------
// Kernel 1: WhT (bf16, [bh*D+d][n]) = (h @ W)^T per head, plus e_src/e_dst
// (pre-scaled by log2e so attn uses exp2 directly).
// ---------------------------------------------------------------------------
constexpr int NPB = 16;  // h-rows per block

__global__ __launch_bounds__(256) void wh_kernel(
    const float* __restrict__ h, const float* __restrict__ W,
    const float* __restrict__ a, u16* __restrict__ WhT,
    float* __restrict__ es, float* __restrict__ ed) {
  __shared__ float hsh[NPB][FIN];
  __shared__ float part[NPB][H_][D_];
  const int t = threadIdx.x;
  const int fh = t >> 7, hh = (t >> 5) & 3, d = t & 31;

  float Wr[64];
#pragma unroll
  for (int ff = 0; ff < 64; ++ff)
    Wr[ff] = W[hh * (FIN * D_) + (fh * 64 + ff) * D_ + d];

  const int n0 = blockIdx.x * NPB;
  for (int idx = t; idx < NPB * FIN; idx += 256)
    hsh[idx >> 7][idx & 127] = h[(size_t)n0 * FIN + idx];
  __syncthreads();

  float accs[NPB];
#pragma unroll
  for (int r = 0; r < NPB; ++r) {
    float acc = 0.f;
    const float* hr = &hsh[r][fh * 64];
#pragma unroll
    for (int f4 = 0; f4 < 16; ++f4) {
      float4 hv = *(const float4*)(hr + f4 * 4);
      acc += hv.x * Wr[f4 * 4 + 0];
      acc += hv.y * Wr[f4 * 4 + 1];
      acc += hv.z * Wr[f4 * 4 + 2];
      acc += hv.w * Wr[f4 * 4 + 3];
    }
    accs[r] = acc;
  }
  if (fh == 0) {
#pragma unroll
    for (int r = 0; r < NPB; ++r) part[r][hh][d] = accs[r];
  }
  __syncthreads();
  if (fh == 1) {
    const int b = n0 / N_;
    const int bh = b * H_ + hh;
    const int n0r = n0 & (N_ - 1);
    const float asrc = a[hh * 2 * D_ + d];
    const float adst = a[hh * 2 * D_ + D_ + d];
    union { u16 s[16]; uint4 q[2]; } wbuf;
#pragma unroll
    for (int r = 0; r < NPB; ++r) {
      const float wh = accs[r] + part[r][hh][d];
      union { __hip_bfloat16 h; u16 u; } cv;
      cv.h = __float2bfloat16(wh);
      wbuf.s[r] = cv.u;
      float vs = wh * asrc, vd = wh * adst;
#pragma unroll
      for (int o = 16; o >= 1; o >>= 1) {
        vs += __shfl_xor(vs, o, 64);
        vd += __shfl_xor(vd, o, 64);
      }
      if (d == 0) {
        es[(size_t)bh * N_ + n0r + r] = vs * LOG2E;
        ed[(size_t)bh * N_ + n0r + r] = vd * LOG2E;
      }
    }
    u16* dst = WhT + ((size_t)(bh * 32 + d)) * N_ + n0r;
    *(uint4*)dst = wbuf.q[0];
    *(uint4*)(dst + 8) = wbuf.q[1];
  }
}

// ---------------------------------------------------------------------------
// Kernel 2: pack adj into a bitmask (u64 word per 64 cols).
// ---------------------------------------------------------------------------
__global__ __launch_bounds__(256) void pack_kernel(
    const int* __restrict__ adj, unsigned long long* __restrict__ mask) {
  const int gid = blockIdx.x * 256 + threadIdx.x;
  const int wdx = gid >> 6;
  const int lane = threadIdx.x & 63;
  const int i = wdx >> 5;
  const int jb = (wdx & 31) << 6;
  const int v = adj[(size_t)i * N_ + jb + lane];
  const unsigned long long m = __ballot(v > 0);
  if (lane == 0) mask[wdx] = m;
}

// ---------------------------------------------------------------------------
// Kernel 3: fused masked-softmax + MFMA PV.
// 16 rows/block, 4 j-quarter waves, 2048 blocks (8/CU pinned via bounds).
// Tight score math: add/fma/max + sbfe/bfi mask select + raw v_exp_f32.
// ---------------------------------------------------------------------------
constexpr int ROWS = 16;
constexpr int NSTEP = 16;  // 512 k per j-quarter / 32

__global__ __launch_bounds__(256, 8) void attn_kernel(
    const float* __restrict__ es, const float* __restrict__ ed,
    const u16* __restrict__ WhT, const unsigned int* __restrict__ mask32,
    float* __restrict__ out) {
  // arena: [edsh 8192B | maskw 4160B], epilogue overlay: redc [4][16][33] f32
  __shared__ __align__(16) char arena[12352];
  __shared__ float essh[ROWS], rmsh[ROWS];
  __shared__ float sumsh[4][16];

  float* edsh = (float*)arena;
  unsigned int* maskw = (unsigned int*)(arena + 8192);

  const int bh = blockIdx.x >> 7;  // 128 row-tiles per bh
  const int i0 = (blockIdx.x & 127) * ROWS;
  const int tid = threadIdx.x, lane = tid & 63, w = tid >> 6;
  const int jq = w;  // j-quarter per wave

  // ---- prologue: stage ed, mask rows, es ----
  const float* edb = ed + (size_t)bh * N_;
  *(float4*)&edsh[tid * 8] = *(const float4*)(edb + tid * 8);
  *(float4*)&edsh[tid * 8 + 4] = *(const float4*)(edb + tid * 8 + 4);
  const unsigned int* mrow = mask32 + (size_t)i0 * 64;
#pragma unroll
  for (int q = 0; q < 4; ++q) {
    const int idx = tid + q * 256;
    maskw[(idx >> 6) * 65 + (idx & 63)] = mrow[(idx >> 6) * 64 + (idx & 63)];
  }
  if (tid < ROWS) essh[tid] = es[(size_t)bh * N_ + i0 + tid];
  __syncthreads();

  // ---- in-block masked rowmax: q-outer, edv hoisted across 4 rows ----
  {
    const unsigned int NEGU = __float_as_uint(-3.0e38f);
    float mx0 = -3.0e38f, mx1 = -3.0e38f, mx2 = -3.0e38f, mx3 = -3.0e38f;
    const int l31 = lane & 31, lh = lane >> 5;
#pragma unroll 8
    for (int q = 0; q < 32; ++q) {
      const float edv = edsh[q * 64 + lane];
      const int base = w * 4 * 65 + q * 2 + lh;
      const int b0 = __builtin_amdgcn_sbfe((int)maskw[base], l31, 1);
      const int b1 = __builtin_amdgcn_sbfe((int)maskw[base + 65], l31, 1);
      const int b2 = __builtin_amdgcn_sbfe((int)maskw[base + 130], l31, 1);
      const int b3 = __builtin_amdgcn_sbfe((int)maskw[base + 195], l31, 1);
      mx0 = fmaxf(mx0, bitsel(b0, edv, NEGU));
      mx1 = fmaxf(mx1, bitsel(b1, edv, NEGU));
      mx2 = fmaxf(mx2, bitsel(b2, edv, NEGU));
      mx3 = fmaxf(mx3, bitsel(b3, edv, NEGU));
    }
#pragma unroll
    for (int o = 32; o >= 1; o >>= 1) {
      mx0 = fmaxf(mx0, __shfl_xor(mx0, o, 64));
      mx1 = fmaxf(mx1, __shfl_xor(mx1, o, 64));
      mx2 = fmaxf(mx2, __shfl_xor(mx2, o, 64));
      mx3 = fmaxf(mx3, __shfl_xor(mx3, o, 64));
    }
    if (lane == 0) {
      rmsh[w * 4 + 0] = mx0;
      rmsh[w * 4 + 1] = mx1;
      rmsh[w * 4 + 2] = mx2;
      rmsh[w * 4 + 3] = mx3;
    }
  }
  __syncthreads();

  const int row16 = lane & 15, kg = lane >> 4;
  const float esr = essh[row16];
  const float xm = esr + rmsh[row16];
  const float mxr = fmaxf(xm, 0.2f * xm);  // exact masked row max (scaled)
  const float cpos = esr - mxr;            // z_pos = ed + cpos
  const float cneg = 0.2f * esr - mxr;     // z_neg = fma(ed, 0.2, cneg)
  const unsigned int NEGZ = __float_as_uint(-1.0e30f);

  // B-fragment base: d-row = row16 (c0) / row16+16 (c1), k offset kg*8.
  const u16* wb0 = WhT + ((size_t)(bh * 32 + row16)) * N_ + jq * 512 + kg * 8;
  const u16* wb1 = wb0 + (size_t)16 * N_;
  const unsigned int* mwp = maskw + row16 * 65 + jq * 16;
  const float* edq = edsh + jq * 512 + kg * 8;
  const int kg8 = kg << 3;

  // all-ones bf16 B fragment for the denominator MFMA
  short8 ones;
#pragma unroll
  for (int q = 0; q < 8; ++q) ones[q] = (short)0x3F80;

  f32x4 c0 = {}, c1 = {}, csum = {};

#pragma unroll 4
  for (int s = 0; s < NSTEP; ++s) {
    const short8 b0 = *(const short8*)(wb0 + s * 32);
    const short8 b1 = *(const short8*)(wb1 + s * 32);

    const unsigned int mw = mwp[s] >> kg8;  // this lane's 8 mask bits at [7:0]
    const float4 ea = *(const float4*)(edq + s * 32);
    const float4 eb = *(const float4*)(edq + s * 32 + 4);
    const float ev[8] = {ea.x, ea.y, ea.z, ea.w, eb.x, eb.y, eb.z, eb.w};
    float p[8];
#pragma unroll
    for (int j = 0; j < 8; ++j) {
      const float edv = ev[j];
      const float zp = edv + cpos;
      const float zn = __builtin_fmaf(edv, 0.2f, cneg);
      const float z = fmaxf(zp, zn);  // leaky via max (slope 1 vs 0.2)
      const int mbit = __builtin_amdgcn_sbfe((int)mw, j, 1);
      p[j] = __builtin_amdgcn_exp2f(bitsel(mbit, z, NEGZ));
    }
    union { unsigned int u[4]; short8 v8; } af;
    asm("v_cvt_pk_bf16_f32 %0, %1, %2" : "=v"(af.u[0]) : "v"(p[0]), "v"(p[1]));
    asm("v_cvt_pk_bf16_f32 %0, %1, %2" : "=v"(af.u[1]) : "v"(p[2]), "v"(p[3]));
    asm("v_cvt_pk_bf16_f32 %0, %1, %2" : "=v"(af.u[2]) : "v"(p[4]), "v"(p[5]));
    asm("v_cvt_pk_bf16_f32 %0, %1, %2" : "=v"(af.u[3]) : "v"(p[6]), "v"(p[7]));

    c0 = __builtin_amdgcn_mfma_f32_16x16x32_bf16(af.v8, b0, c0, 0, 0, 0);
    c1 = __builtin_amdgcn_mfma_f32_16x16x32_bf16(af.v8, b1, c1, 0, 0, 0);
    csum = __builtin_amdgcn_mfma_f32_16x16x32_bf16(af.v8, ones, csum, 0, 0, 0);
  }

  __syncthreads();  // edsh/mask dead from here

  // ---- epilogue: overlay redc onto arena; combine 4 j-quarters ----
  float* redc = (float*)arena;  // [4][16][33]
#pragma unroll
  for (int r = 0; r < 4; ++r) {
    redc[(jq * 16 + kg * 4 + r) * 33 + row16] = c0[r];
    redc[(jq * 16 + kg * 4 + r) * 33 + 16 + row16] = c1[r];
  }
  if (row16 == 0) {
#pragma unroll
    for (int r = 0; r < 4; ++r) sumsh[jq][kg * 4 + r] = csum[r];
  }
  __syncthreads();

  if (tid < 128) {
    const int r = tid >> 3;
    const int c4 = (tid & 7) * 4;
    const float inv =
        1.f / fmaxf(sumsh[0][r] + sumsh[1][r] + sumsh[2][r] + sumsh[3][r],
                    1e-30f);
    float4 o;
    const float* p0 = &redc[(0 * 16 + r) * 33 + c4];
    const float* p1 = &redc[(1 * 16 + r) * 33 + c4];
    const float* p2 = &redc[(2 * 16 + r) * 33 + c4];
    const float* p3 = &redc[(3 * 16 + r) * 33 + c4];
    o.x = (p0[0] + p1[0] + p2[0] + p3[0]) * inv;
    o.y = (p0[1] + p1[1] + p2[1] + p3[1]) * inv;
    o.z = (p0[2] + p1[2] + p2[2] + p3[2]) * inv;
    o.w = (p0[3] + p1[3] + p2[3] + p3[3]) * inv;
    const int b = bh >> 2, hh = bh & 3;
    *(float4*)&out[((size_t)(b * N_ + i0 + r)) * (H_ * D_) + hh * 32 + c4] = o;
  }
}

// ---------------------------------------------------------------------------
extern "C" void kernel_launch(void* const* d_in, const int* in_sizes, int n_in,
                              void* d_out, int out_size, void* d_ws,
                              size_t ws_size, hipStream_t stream) {
  const float* h = (const float*)d_in[0];
  const int* adj = (const int*)d_in[1];
  const float* W = (const float*)d_in[2];
  const float* a = (const float*)d_in[3];
  char* ws = (char*)d_ws;
  u16* WhT = (u16*)ws;                                   // 2 MB
  float* es = (float*)(ws + (2u << 20));                 // 128 KB
  float* ed = (float*)(ws + (2u << 20) + (128u << 10));  // 128 KB
  unsigned long long* mask =
      (unsigned long long*)(ws + (2u << 20) + (256u << 10));  // 512 KB
  float* out = (float*)d_out;

  wh_kernel<<<B_ * N_ / NPB, 256, 0, stream>>>(h, W, a, WhT, es, ed);
  pack_kernel<<<N_ * N_ / 256, 256, 0, stream>>>(adj, mask);
  attn_kernel<<<BH * (N_ / ROWS), 256, 0, stream>>>(
      es, ed, WhT, (const unsigned int*)mask, out);
}

// Round 11
// 124.826 us; speedup vs baseline: 1.4512x; 1.0050x over previous
//
#include <hip/hip_runtime.h>
#include <hip/hip_bf16.h>

typedef unsigned short u16;
using f32x4 = __attribute__((ext_vector_type(4))) float;
using short8 = __attribute__((ext_vector_type(8))) short;

constexpr int B_ = 4, N_ = 2048, FIN = 128, H_ = 4, D_ = 32;
constexpr int BH = B_ * H_;
constexpr float LOG2E = 1.4426950408889634f;

// bit-select: m is 0 or -1 per lane; returns m ? a : b(bits).  -> v_bfi_b32
static __device__ __forceinline__ float bitsel(int m, float a, unsigned int bu) {
  return __uint_as_float((__float_as_uint(a) & (unsigned)m) | (bu & ~(unsigned)m));
}

// ---------------------------------------------------------------------------
// Kernel 1: WhT (bf16, [bh*D+d][n]) = (h @ W)^T per head, plus e_src/e_dst
// (pre-scaled by log2e so attn uses exp2 directly).
// ---------------------------------------------------------------------------
constexpr int NPB = 16;  // h-rows per block

__global__ __launch_bounds__(256) void wh_kernel(
    const float* __restrict__ h, const float* __restrict__ W,
    const float* __restrict__ a, u16* __restrict__ WhT,
    float* __restrict__ es, float* __restrict__ ed) {
  __shared__ float hsh[NPB][FIN];
  __shared__ float part[NPB][H_][D_];
  const int t = threadIdx.x;
  const int fh = t >> 7, hh = (t >> 5) & 3, d = t & 31;

  float Wr[64];
#pragma unroll
  for (int ff = 0; ff < 64; ++ff)
    Wr[ff] = W[hh * (FIN * D_) + (fh * 64 + ff) * D_ + d];

  const int n0 = blockIdx.x * NPB;
  for (int idx = t; idx < NPB * FIN; idx += 256)
    hsh[idx >> 7][idx & 127] = h[(size_t)n0 * FIN + idx];
  __syncthreads();

  float accs[NPB];
#pragma unroll
  for (int r = 0; r < NPB; ++r) {
    float acc = 0.f;
    const float* hr = &hsh[r][fh * 64];
#pragma unroll
    for (int f4 = 0; f4 < 16; ++f4) {
      float4 hv = *(const float4*)(hr + f4 * 4);
      acc += hv.x * Wr[f4 * 4 + 0];
      acc += hv.y * Wr[f4 * 4 + 1];
      acc += hv.z * Wr[f4 * 4 + 2];
      acc += hv.w * Wr[f4 * 4 + 3];
    }
    accs[r] = acc;
  }
  if (fh == 0) {
#pragma unroll
    for (int r = 0; r < NPB; ++r) part[r][hh][d] = accs[r];
  }
  __syncthreads();
  if (fh == 1) {
    const int b = n0 / N_;
    const int bh = b * H_ + hh;
    const int n0r = n0 & (N_ - 1);
    const float asrc = a[hh * 2 * D_ + d];
    const float adst = a[hh * 2 * D_ + D_ + d];
    union { u16 s[16]; uint4 q[2]; } wbuf;
#pragma unroll
    for (int r = 0; r < NPB; ++r) {
      const float wh = accs[r] + part[r][hh][d];
      union { __hip_bfloat16 h; u16 u; } cv;
      cv.h = __float2bfloat16(wh);
      wbuf.s[r] = cv.u;
      float vs = wh * asrc, vd = wh * adst;
#pragma unroll
      for (int o = 16; o >= 1; o >>= 1) {
        vs += __shfl_xor(vs, o, 64);
        vd += __shfl_xor(vd, o, 64);
      }
      if (d == 0) {
        es[(size_t)bh * N_ + n0r + r] = vs * LOG2E;
        ed[(size_t)bh * N_ + n0r + r] = vd * LOG2E;
      }
    }
    u16* dst = WhT + ((size_t)(bh * 32 + d)) * N_ + n0r;
    *(uint4*)dst = wbuf.q[0];
    *(uint4*)(dst + 8) = wbuf.q[1];
  }
}

// ---------------------------------------------------------------------------
// Kernel 2: pack adj into a bitmask; grid-stride, 8 words per wave.
// ---------------------------------------------------------------------------
constexpr int PACKW = N_ * N_ / 64;  // 65536 words

__global__ __launch_bounds__(256) void pack_kernel(
    const int* __restrict__ adj, unsigned long long* __restrict__ mask) {
  const int wave = (blockIdx.x * 256 + threadIdx.x) >> 6;  // 8192 waves
  const int lane = threadIdx.x & 63;
#pragma unroll
  for (int t = 0; t < 8; ++t) {
    const int wdx = wave * 8 + t;
    const int i = wdx >> 5;
    const int jb = (wdx & 31) << 6;
    const int v = adj[(size_t)i * N_ + jb + lane];
    const unsigned long long m = __ballot(v > 0);
    if (lane == 0) mask[wdx] = m;
  }
}

// ---------------------------------------------------------------------------
// Kernel 3: fused masked-softmax + MFMA PV.
// 16 rows/block, 4 j-quarter waves, 2048 blocks (8/CU pinned).
// Mask words preloaded to VGPRs; select-after-exp; depth-2 b prefetch.
// ---------------------------------------------------------------------------
constexpr int ROWS = 16;
constexpr int NSTEP = 16;  // 512 k per j-quarter / 32

__global__ __launch_bounds__(256, 8) void attn_kernel(
    const float* __restrict__ es, const float* __restrict__ ed,
    const u16* __restrict__ WhT, const unsigned int* __restrict__ mask32,
    float* __restrict__ out) {
  // arena: [edsh 8192B | maskw 4160B], epilogue overlay: redc [4][16][33] f32
  __shared__ __align__(16) char arena[12352];
  __shared__ float essh[ROWS], rmsh[ROWS];
  __shared__ float sumsh[4][16];

  float* edsh = (float*)arena;
  unsigned int* maskw = (unsigned int*)(arena + 8192);

  const int bh = blockIdx.x >> 7;  // 128 row-tiles per bh
  const int i0 = (blockIdx.x & 127) * ROWS;
  const int tid = threadIdx.x, lane = tid & 63, w = tid >> 6;
  const int jq = w;  // j-quarter per wave

  // ---- prologue: stage ed, mask rows, es ----
  const float* edb = ed + (size_t)bh * N_;
  *(float4*)&edsh[tid * 8] = *(const float4*)(edb + tid * 8);
  *(float4*)&edsh[tid * 8 + 4] = *(const float4*)(edb + tid * 8 + 4);
  const unsigned int* mrow = mask32 + (size_t)i0 * 64;
#pragma unroll
  for (int q = 0; q < 4; ++q) {
    const int idx = tid + q * 256;
    maskw[(idx >> 6) * 65 + (idx & 63)] = mrow[(idx >> 6) * 64 + (idx & 63)];
  }
  if (tid < ROWS) essh[tid] = es[(size_t)bh * N_ + i0 + tid];
  __syncthreads();

  // ---- in-block masked rowmax: q-outer, edv hoisted across 4 rows ----
  {
    const unsigned int NEGU = __float_as_uint(-3.0e38f);
    float mx0 = -3.0e38f, mx1 = -3.0e38f, mx2 = -3.0e38f, mx3 = -3.0e38f;
    const int l31 = lane & 31, lh = lane >> 5;
#pragma unroll 8
    for (int q = 0; q < 32; ++q) {
      const float edv = edsh[q * 64 + lane];
      const int base = w * 4 * 65 + q * 2 + lh;
      const int b0 = __builtin_amdgcn_sbfe((int)maskw[base], l31, 1);
      const int b1 = __builtin_amdgcn_sbfe((int)maskw[base + 65], l31, 1);
      const int b2 = __builtin_amdgcn_sbfe((int)maskw[base + 130], l31, 1);
      const int b3 = __builtin_amdgcn_sbfe((int)maskw[base + 195], l31, 1);
      mx0 = fmaxf(mx0, bitsel(b0, edv, NEGU));
      mx1 = fmaxf(mx1, bitsel(b1, edv, NEGU));
      mx2 = fmaxf(mx2, bitsel(b2, edv, NEGU));
      mx3 = fmaxf(mx3, bitsel(b3, edv, NEGU));
    }
#pragma unroll
    for (int o = 32; o >= 1; o >>= 1) {
      mx0 = fmaxf(mx0, __shfl_xor(mx0, o, 64));
      mx1 = fmaxf(mx1, __shfl_xor(mx1, o, 64));
      mx2 = fmaxf(mx2, __shfl_xor(mx2, o, 64));
      mx3 = fmaxf(mx3, __shfl_xor(mx3, o, 64));
    }
    if (lane == 0) {
      rmsh[w * 4 + 0] = mx0;
      rmsh[w * 4 + 1] = mx1;
      rmsh[w * 4 + 2] = mx2;
      rmsh[w * 4 + 3] = mx3;
    }
  }
  __syncthreads();

  const int row16 = lane & 15, kg = lane >> 4;
  const float esr = essh[row16];
  const float xm = esr + rmsh[row16];
  const float mxr = fmaxf(xm, 0.2f * xm);  // exact masked row max (scaled)
  const float cpos = esr - mxr;            // z_pos = ed + cpos
  const float cneg = 0.2f * esr - mxr;     // z_neg = fma(ed, 0.2, cneg)

  // ---- preload this wave's 16 mask words into VGPRs ----
  const unsigned int* mwp = maskw + row16 * 65 + jq * 16;
  const int kg8 = kg << 3;
  unsigned int mreg[16];
#pragma unroll
  for (int s = 0; s < NSTEP; ++s) mreg[s] = mwp[s] >> kg8;  // bits at [7:0]

  // B-fragment base: d-row = row16 (c0) / row16+16 (c1), k offset kg*8.
  const u16* wb0 = WhT + ((size_t)(bh * 32 + row16)) * N_ + jq * 512 + kg * 8;
  const u16* wb1 = wb0 + (size_t)16 * N_;
  const float* edq = edsh + jq * 512 + kg * 8;

  // all-ones bf16 B fragment for the denominator MFMA
  short8 ones;
#pragma unroll
  for (int q = 0; q < 8; ++q) ones[q] = (short)0x3F80;

  f32x4 c0 = {}, c1 = {}, csum = {};
  short8 b0 = *(const short8*)wb0;
  short8 b1 = *(const short8*)wb1;

#pragma unroll
  for (int s = 0; s < NSTEP; ++s) {
    const int sn = (s + 1 < NSTEP) ? (s + 1) : s;
    const short8 nb0 = *(const short8*)(wb0 + sn * 32);
    const short8 nb1 = *(const short8*)(wb1 + sn * 32);

    const unsigned int mw = mreg[s];
    const float4 ea = *(const float4*)(edq + s * 32);
    const float4 eb = *(const float4*)(edq + s * 32 + 4);
    const float ev[8] = {ea.x, ea.y, ea.z, ea.w, eb.x, eb.y, eb.z, eb.w};
    float p[8];
#pragma unroll
    for (int j = 0; j < 8; ++j) {
      const float edv = ev[j];
      const float zp = edv + cpos;
      const float zn = __builtin_fmaf(edv, 0.2f, cneg);
      const float z = fmaxf(zp, zn);  // leaky via max (slope 1 vs 0.2)
      const float e = __builtin_amdgcn_exp2f(z);  // may be inf if unmasked
      const int mbit = __builtin_amdgcn_sbfe((int)mw, j, 1);
      p[j] = bitsel(mbit, e, 0u);  // select-after-exp; inf killed here
    }
    union { unsigned int u[4]; short8 v8; } af;
    asm("v_cvt_pk_bf16_f32 %0, %1, %2" : "=v"(af.u[0]) : "v"(p[0]), "v"(p[1]));
    asm("v_cvt_pk_bf16_f32 %0, %1, %2" : "=v"(af.u[1]) : "v"(p[2]), "v"(p[3]));
    asm("v_cvt_pk_bf16_f32 %0, %1, %2" : "=v"(af.u[2]) : "v"(p[4]), "v"(p[5]));
    asm("v_cvt_pk_bf16_f32 %0, %1, %2" : "=v"(af.u[3]) : "v"(p[6]), "v"(p[7]));

    c0 = __builtin_amdgcn_mfma_f32_16x16x32_bf16(af.v8, b0, c0, 0, 0, 0);
    c1 = __builtin_amdgcn_mfma_f32_16x16x32_bf16(af.v8, b1, c1, 0, 0, 0);
    csum = __builtin_amdgcn_mfma_f32_16x16x32_bf16(af.v8, ones, csum, 0, 0, 0);
    b0 = nb0;
    b1 = nb1;
  }

  __syncthreads();  // edsh/mask dead from here

  // ---- epilogue: overlay redc onto arena; combine 4 j-quarters ----
  float* redc = (float*)arena;  // [4][16][33]
#pragma unroll
  for (int r = 0; r < 4; ++r) {
    redc[(jq * 16 + kg * 4 + r) * 33 + row16] = c0[r];
    redc[(jq * 16 + kg * 4 + r) * 33 + 16 + row16] = c1[r];
  }
  if (row16 == 0) {
#pragma unroll
    for (int r = 0; r < 4; ++r) sumsh[jq][kg * 4 + r] = csum[r];
  }
  __syncthreads();

  if (tid < 128) {
    const int r = tid >> 3;
    const int c4 = (tid & 7) * 4;
    const float inv =
        1.f / fmaxf(sumsh[0][r] + sumsh[1][r] + sumsh[2][r] + sumsh[3][r],
                    1e-30f);
    float4 o;
    const float* p0 = &redc[(0 * 16 + r) * 33 + c4];
    const float* p1 = &redc[(1 * 16 + r) * 33 + c4];
    const float* p2 = &redc[(2 * 16 + r) * 33 + c4];
    const float* p3 = &redc[(3 * 16 + r) * 33 + c4];
    o.x = (p0[0] + p1[0] + p2[0] + p3[0]) * inv;
    o.y = (p0[1] + p1[1] + p2[1] + p3[1]) * inv;
    o.z = (p0[2] + p1[2] + p2[2] + p3[2]) * inv;
    o.w = (p0[3] + p1[3] + p2[3] + p3[3]) * inv;
    const int b = bh >> 2, hh = bh & 3;
    *(float4*)&out[((size_t)(b * N_ + i0 + r)) * (H_ * D_) + hh * 32 + c4] = o;
  }
}

// ---------------------------------------------------------------------------
extern "C" void kernel_launch(void* const* d_in, const int* in_sizes, int n_in,
                              void* d_out, int out_size, void* d_ws,
                              size_t ws_size, hipStream_t stream) {
  const float* h = (const float*)d_in[0];
  const int* adj = (const int*)d_in[1];
  const float* W = (const float*)d_in[2];
  const float* a = (const float*)d_in[3];
  char* ws = (char*)d_ws;
  u16* WhT = (u16*)ws;                                   // 2 MB
  float* es = (float*)(ws + (2u << 20));                 // 128 KB
  float* ed = (float*)(ws + (2u << 20) + (128u << 10));  // 128 KB
  unsigned long long* mask =
      (unsigned long long*)(ws + (2u << 20) + (256u << 10));  // 512 KB
  float* out = (float*)d_out;

  wh_kernel<<<B_ * N_ / NPB, 256, 0, stream>>>(h, W, a, WhT, es, ed);
  pack_kernel<<<PACKW / (8 * 4), 256, 0, stream>>>(adj, mask);
  attn_kernel<<<BH * (N_ / ROWS), 256, 0, stream>>>(
      es, ed, WhT, (const unsigned int*)mask, out);
}

// Round 12
// 123.686 us; speedup vs baseline: 1.4645x; 1.0092x over previous
//
#include <hip/hip_runtime.h>
#include <hip/hip_bf16.h>

typedef unsigned short u16;
using f32x4 = __attribute__((ext_vector_type(4))) float;
using f32x2 = __attribute__((ext_vector_type(2))) float;
using short8 = __attribute__((ext_vector_type(8))) short;

constexpr int B_ = 4, N_ = 2048, FIN = 128, H_ = 4, D_ = 32;
constexpr int BH = B_ * H_;
constexpr float LOG2E = 1.4426950408889634f;

// bit-select: m is 0 or -1 per lane; returns m ? a : b(bits).  -> v_bfi/v_and
static __device__ __forceinline__ float bitsel(int m, float a, unsigned int bu) {
  return __uint_as_float((__float_as_uint(a) & (unsigned)m) | (bu & ~(unsigned)m));
}

// ---------------------------------------------------------------------------
// Kernel 1: WhT (bf16, [bh*D+d][n]) = (h @ W)^T per head, plus e_src/e_dst
// (pre-scaled by log2e so attn uses exp2 directly).
// ---------------------------------------------------------------------------
constexpr int NPB = 16;  // h-rows per block

__global__ __launch_bounds__(256) void wh_kernel(
    const float* __restrict__ h, const float* __restrict__ W,
    const float* __restrict__ a, u16* __restrict__ WhT,
    float* __restrict__ es, float* __restrict__ ed) {
  __shared__ float hsh[NPB][FIN];
  __shared__ float part[NPB][H_][D_];
  const int t = threadIdx.x;
  const int fh = t >> 7, hh = (t >> 5) & 3, d = t & 31;

  float Wr[64];
#pragma unroll
  for (int ff = 0; ff < 64; ++ff)
    Wr[ff] = W[hh * (FIN * D_) + (fh * 64 + ff) * D_ + d];

  const int n0 = blockIdx.x * NPB;
  for (int idx = t; idx < NPB * FIN; idx += 256)
    hsh[idx >> 7][idx & 127] = h[(size_t)n0 * FIN + idx];
  __syncthreads();

  float accs[NPB];
#pragma unroll
  for (int r = 0; r < NPB; ++r) {
    float acc = 0.f;
    const float* hr = &hsh[r][fh * 64];
#pragma unroll
    for (int f4 = 0; f4 < 16; ++f4) {
      float4 hv = *(const float4*)(hr + f4 * 4);
      acc += hv.x * Wr[f4 * 4 + 0];
      acc += hv.y * Wr[f4 * 4 + 1];
      acc += hv.z * Wr[f4 * 4 + 2];
      acc += hv.w * Wr[f4 * 4 + 3];
    }
    accs[r] = acc;
  }
  if (fh == 0) {
#pragma unroll
    for (int r = 0; r < NPB; ++r) part[r][hh][d] = accs[r];
  }
  __syncthreads();
  if (fh == 1) {
    const int b = n0 / N_;
    const int bh = b * H_ + hh;
    const int n0r = n0 & (N_ - 1);
    const float asrc = a[hh * 2 * D_ + d];
    const float adst = a[hh * 2 * D_ + D_ + d];
    union { u16 s[16]; uint4 q[2]; } wbuf;
#pragma unroll
    for (int r = 0; r < NPB; ++r) {
      const float wh = accs[r] + part[r][hh][d];
      union { __hip_bfloat16 h; u16 u; } cv;
      cv.h = __float2bfloat16(wh);
      wbuf.s[r] = cv.u;
      float vs = wh * asrc, vd = wh * adst;
#pragma unroll
      for (int o = 16; o >= 1; o >>= 1) {
        vs += __shfl_xor(vs, o, 64);
        vd += __shfl_xor(vd, o, 64);
      }
      if (d == 0) {
        es[(size_t)bh * N_ + n0r + r] = vs * LOG2E;
        ed[(size_t)bh * N_ + n0r + r] = vd * LOG2E;
      }
    }
    u16* dst = WhT + ((size_t)(bh * 32 + d)) * N_ + n0r;
    *(uint4*)dst = wbuf.q[0];
    *(uint4*)(dst + 8) = wbuf.q[1];
  }
}

// ---------------------------------------------------------------------------
// Kernel 2: pack adj into a bitmask; grid-stride, 8 words per wave.
// ---------------------------------------------------------------------------
constexpr int PACKW = N_ * N_ / 64;  // 65536 words

__global__ __launch_bounds__(256) void pack_kernel(
    const int* __restrict__ adj, unsigned long long* __restrict__ mask) {
  const int wave = (blockIdx.x * 256 + threadIdx.x) >> 6;  // 8192 waves
  const int lane = threadIdx.x & 63;
#pragma unroll
  for (int t = 0; t < 8; ++t) {
    const int wdx = wave * 8 + t;
    const int i = wdx >> 5;
    const int jb = (wdx & 31) << 6;
    const int v = adj[(size_t)i * N_ + jb + lane];
    const unsigned long long m = __ballot(v > 0);
    if (lane == 0) mask[wdx] = m;
  }
}

// ---------------------------------------------------------------------------
// Kernel 3: fused masked-softmax + MFMA PV.
// 16 rows/block, 4 j-quarter waves, 2048 blocks (8/CU pinned).
// Depth-2 named-register b prefetch; f32x2 packed score math.
// ---------------------------------------------------------------------------
constexpr int ROWS = 16;
constexpr int NSTEP = 16;  // 512 k per j-quarter / 32

__global__ __launch_bounds__(256, 8) void attn_kernel(
    const float* __restrict__ es, const float* __restrict__ ed,
    const u16* __restrict__ WhT, const unsigned int* __restrict__ mask32,
    float* __restrict__ out) {
  // arena: [edsh 8192B | maskw 4160B], epilogue overlay: redc [4][16][33] f32
  __shared__ __align__(16) char arena[12352];
  __shared__ float essh[ROWS], rmsh[ROWS];
  __shared__ float sumsh[4][16];

  float* edsh = (float*)arena;
  unsigned int* maskw = (unsigned int*)(arena + 8192);

  const int bh = blockIdx.x >> 7;  // 128 row-tiles per bh
  const int i0 = (blockIdx.x & 127) * ROWS;
  const int tid = threadIdx.x, lane = tid & 63, w = tid >> 6;
  const int jq = w;  // j-quarter per wave

  // ---- prologue: stage ed, mask rows, es ----
  const float* edb = ed + (size_t)bh * N_;
  *(float4*)&edsh[tid * 8] = *(const float4*)(edb + tid * 8);
  *(float4*)&edsh[tid * 8 + 4] = *(const float4*)(edb + tid * 8 + 4);
  const unsigned int* mrow = mask32 + (size_t)i0 * 64;
#pragma unroll
  for (int q = 0; q < 4; ++q) {
    const int idx = tid + q * 256;
    maskw[(idx >> 6) * 65 + (idx & 63)] = mrow[(idx >> 6) * 64 + (idx & 63)];
  }
  if (tid < ROWS) essh[tid] = es[(size_t)bh * N_ + i0 + tid];
  __syncthreads();

  // ---- in-block masked rowmax: q-outer, edv hoisted across 4 rows ----
  {
    const unsigned int NEGU = __float_as_uint(-3.0e38f);
    float mx0 = -3.0e38f, mx1 = -3.0e38f, mx2 = -3.0e38f, mx3 = -3.0e38f;
    const int l31 = lane & 31, lh = lane >> 5;
#pragma unroll 8
    for (int q = 0; q < 32; ++q) {
      const float edv = edsh[q * 64 + lane];
      const int base = w * 4 * 65 + q * 2 + lh;
      const int b0 = __builtin_amdgcn_sbfe((int)maskw[base], l31, 1);
      const int b1 = __builtin_amdgcn_sbfe((int)maskw[base + 65], l31, 1);
      const int b2 = __builtin_amdgcn_sbfe((int)maskw[base + 130], l31, 1);
      const int b3 = __builtin_amdgcn_sbfe((int)maskw[base + 195], l31, 1);
      mx0 = fmaxf(mx0, bitsel(b0, edv, NEGU));
      mx1 = fmaxf(mx1, bitsel(b1, edv, NEGU));
      mx2 = fmaxf(mx2, bitsel(b2, edv, NEGU));
      mx3 = fmaxf(mx3, bitsel(b3, edv, NEGU));
    }
#pragma unroll
    for (int o = 32; o >= 1; o >>= 1) {
      mx0 = fmaxf(mx0, __shfl_xor(mx0, o, 64));
      mx1 = fmaxf(mx1, __shfl_xor(mx1, o, 64));
      mx2 = fmaxf(mx2, __shfl_xor(mx2, o, 64));
      mx3 = fmaxf(mx3, __shfl_xor(mx3, o, 64));
    }
    if (lane == 0) {
      rmsh[w * 4 + 0] = mx0;
      rmsh[w * 4 + 1] = mx1;
      rmsh[w * 4 + 2] = mx2;
      rmsh[w * 4 + 3] = mx3;
    }
  }
  __syncthreads();

  const int row16 = lane & 15, kg = lane >> 4;
  const float esr = essh[row16];
  const float xm = esr + rmsh[row16];
  const float mxr = fmaxf(xm, 0.2f * xm);  // exact masked row max (scaled)
  const f32x2 cpos2 = {esr - mxr, esr - mxr};
  const f32x2 cneg2 = {0.2f * esr - mxr, 0.2f * esr - mxr};

  const unsigned int* mwp = maskw + row16 * 65 + jq * 16;
  const int kg8 = kg << 3;

  // B-fragment base: d-row = row16 (c0) / row16+16 (c1), k offset kg*8.
  const u16* wb0 = WhT + ((size_t)(bh * 32 + row16)) * N_ + jq * 512 + kg * 8;
  const u16* wb1 = wb0 + (size_t)16 * N_;
  const float* edq = edsh + jq * 512 + kg * 8;

  // all-ones bf16 B fragment for the denominator MFMA
  short8 ones;
#pragma unroll
  for (int q = 0; q < 8; ++q) ones[q] = (short)0x3F80;

  f32x4 c0 = {}, c1 = {}, csum = {};
  // depth-2 software pipeline, named registers only
  short8 ba0 = *(const short8*)wb0;
  short8 ba1 = *(const short8*)wb1;
  short8 bb0 = *(const short8*)(wb0 + 32);
  short8 bb1 = *(const short8*)(wb1 + 32);

#pragma unroll
  for (int s = 0; s < NSTEP; ++s) {
    const int sn = (s + 2 < NSTEP) ? (s + 2) : s;
    const short8 nb0 = *(const short8*)(wb0 + sn * 32);
    const short8 nb1 = *(const short8*)(wb1 + sn * 32);

    const unsigned int mw = mwp[s] >> kg8;  // 8 mask bits at [7:0]
    const float4 ea = *(const float4*)(edq + s * 32);
    const float4 eb = *(const float4*)(edq + s * 32 + 4);
    const f32x2 ev2[4] = {{ea.x, ea.y}, {ea.z, ea.w}, {eb.x, eb.y}, {eb.z, eb.w}};
    float p[8];
#pragma unroll
    for (int jj = 0; jj < 4; ++jj) {
      const f32x2 e2 = ev2[jj];
      const f32x2 zp = e2 + cpos2;          // v_pk_add_f32
      const f32x2 zn = e2 * 0.2f + cneg2;   // v_pk_fma_f32
      const float z0 = fmaxf(zp.x, zn.x);   // leaky via max (slope 1 vs 0.2)
      const float z1 = fmaxf(zp.y, zn.y);
      const float e0 = __builtin_amdgcn_exp2f(z0);
      const float e1 = __builtin_amdgcn_exp2f(z1);
      const int m0 = __builtin_amdgcn_sbfe((int)mw, 2 * jj, 1);
      const int m1 = __builtin_amdgcn_sbfe((int)mw, 2 * jj + 1, 1);
      p[2 * jj] = bitsel(m0, e0, 0u);       // select-after-exp
      p[2 * jj + 1] = bitsel(m1, e1, 0u);
    }
    union { unsigned int u[4]; short8 v8; } af;
    asm("v_cvt_pk_bf16_f32 %0, %1, %2" : "=v"(af.u[0]) : "v"(p[0]), "v"(p[1]));
    asm("v_cvt_pk_bf16_f32 %0, %1, %2" : "=v"(af.u[1]) : "v"(p[2]), "v"(p[3]));
    asm("v_cvt_pk_bf16_f32 %0, %1, %2" : "=v"(af.u[2]) : "v"(p[4]), "v"(p[5]));
    asm("v_cvt_pk_bf16_f32 %0, %1, %2" : "=v"(af.u[3]) : "v"(p[6]), "v"(p[7]));

    c0 = __builtin_amdgcn_mfma_f32_16x16x32_bf16(af.v8, ba0, c0, 0, 0, 0);
    c1 = __builtin_amdgcn_mfma_f32_16x16x32_bf16(af.v8, ba1, c1, 0, 0, 0);
    csum = __builtin_amdgcn_mfma_f32_16x16x32_bf16(af.v8, ones, csum, 0, 0, 0);
    ba0 = bb0; ba1 = bb1;  // rotate pipeline (renamed under full unroll)
    bb0 = nb0; bb1 = nb1;
  }

  __syncthreads();  // edsh/mask dead from here

  // ---- epilogue: overlay redc onto arena; combine 4 j-quarters ----
  float* redc = (float*)arena;  // [4][16][33]
#pragma unroll
  for (int r = 0; r < 4; ++r) {
    redc[(jq * 16 + kg * 4 + r) * 33 + row16] = c0[r];
    redc[(jq * 16 + kg * 4 + r) * 33 + 16 + row16] = c1[r];
  }
  if (row16 == 0) {
#pragma unroll
    for (int r = 0; r < 4; ++r) sumsh[jq][kg * 4 + r] = csum[r];
  }
  __syncthreads();

  if (tid < 128) {
    const int r = tid >> 3;
    const int c4 = (tid & 7) * 4;
    const float inv =
        1.f / fmaxf(sumsh[0][r] + sumsh[1][r] + sumsh[2][r] + sumsh[3][r],
                    1e-30f);
    float4 o;
    const float* p0 = &redc[(0 * 16 + r) * 33 + c4];
    const float* p1 = &redc[(1 * 16 + r) * 33 + c4];
    const float* p2 = &redc[(2 * 16 + r) * 33 + c4];
    const float* p3 = &redc[(3 * 16 + r) * 33 + c4];
    o.x = (p0[0] + p1[0] + p2[0] + p3[0]) * inv;
    o.y = (p0[1] + p1[1] + p2[1] + p3[1]) * inv;
    o.z = (p0[2] + p1[2] + p2[2] + p3[2]) * inv;
    o.w = (p0[3] + p1[3] + p2[3] + p3[3]) * inv;
    const int b = bh >> 2, hh = bh & 3;
    *(float4*)&out[((size_t)(b * N_ + i0 + r)) * (H_ * D_) + hh * 32 + c4] = o;
  }
}

// ---------------------------------------------------------------------------
extern "C" void kernel_launch(void* const* d_in, const int* in_sizes, int n_in,
                              void* d_out, int out_size, void* d_ws,
                              size_t ws_size, hipStream_t stream) {
  const float* h = (const float*)d_in[0];
  const int* adj = (const int*)d_in[1];
  const float* W = (const float*)d_in[2];
  const float* a = (const float*)d_in[3];
  char* ws = (char*)d_ws;
  u16* WhT = (u16*)ws;                                   // 2 MB
  float* es = (float*)(ws + (2u << 20));                 // 128 KB
  float* ed = (float*)(ws + (2u << 20) + (128u << 10));  // 128 KB
  unsigned long long* mask =
      (unsigned long long*)(ws + (2u << 20) + (256u << 10));  // 512 KB
  float* out = (float*)d_out;

  wh_kernel<<<B_ * N_ / NPB, 256, 0, stream>>>(h, W, a, WhT, es, ed);
  pack_kernel<<<PACKW / (8 * 4), 256, 0, stream>>>(adj, mask);
  attn_kernel<<<BH * (N_ / ROWS), 256, 0, stream>>>(
      es, ed, WhT, (const unsigned int*)mask, out);
}